// Round 20
// baseline (338.492 us; speedup 1.0000x reference)
//
#include <hip/hip_runtime.h>
#include <hip/hip_bf16.h>

typedef __bf16 bf16;
typedef __attribute__((ext_vector_type(8))) __bf16 bf16x8;
typedef __attribute__((ext_vector_type(4))) __bf16 bf16x4;
typedef __attribute__((ext_vector_type(4))) float f32x4;

#define MFMA_16x16x32(a, b, c) __builtin_amdgcn_mfma_f32_16x16x32_bf16(a, b, c, 0, 0, 0)

// Problem dims (fixed by the reference)
#define BATCH 4
#define SEQ   4096
#define HID   256
#define FFD   1024
#define MTOT  (BATCH * SEQ)   // 16384
#define NSPLIT 2              // KV splits per q-group (fp32 partials)

// ---------------- fused prep kernel (cast x + 5 weight transposes, 1 launch) ----------------
__global__ __launch_bounds__(256) void prep_kernel(
    const float* __restrict__ x,
    const float* __restrict__ wq, const float* __restrict__ wk, const float* __restrict__ wv,
    const float* __restrict__ w1, const float* __restrict__ w2,
    bf16* __restrict__ xb,
    bf16* __restrict__ wqT, bf16* __restrict__ wkT, bf16* __restrict__ wvT,
    bf16* __restrict__ w1T, bf16* __restrict__ w2T)
{
    int i = blockIdx.x * 256 + threadIdx.x;
    if (i < 1048576) {
        float4 v = ((const float4*)x)[i];
        bf16x4 o;
        o[0] = (bf16)v.x; o[1] = (bf16)v.y; o[2] = (bf16)v.z; o[3] = (bf16)v.w;
        ((bf16x4*)xb)[i] = o;
        return;
    }
    i -= 1048576;
    if (i < 3 * 65536) {
        const float* src = (i < 65536) ? wq : (i < 131072) ? wk : wv;
        bf16* dst = (i < 65536) ? wqT : (i < 131072) ? wkT : wvT;
        int j = i & 65535;
        int r = j >> 8, c = j & 255;
        dst[c * 256 + r] = (bf16)src[j];
        return;
    }
    i -= 3 * 65536;
    if (i < 262144) {                 // w1: [256][1024] -> w1T [1024][256]
        int r = i >> 10, c = i & 1023;
        w1T[c * 256 + r] = (bf16)w1[i];
        return;
    }
    i -= 262144;                      // w2: [1024][256] -> w2T [256][1024]
    int r = i >> 8, c = i & 255;
    w2T[c * 1024 + r] = (bf16)w2[i];
}

// ---------------- QKV projection ----------------
// grid (MTOT/64, 12); blockIdx.y: 0-3 -> q cols, 4-7 -> k cols, 8-11 -> v cols
__global__ __launch_bounds__(256) void qkv_kernel(
    const bf16* __restrict__ xb,                       // [MTOT][256]
    const bf16* __restrict__ wqT, const bf16* __restrict__ wkT, const bf16* __restrict__ wvT,
    const float* __restrict__ bq, const float* __restrict__ bk, const float* __restrict__ bv,
    bf16* __restrict__ q, bf16* __restrict__ k, bf16* __restrict__ vT) // q,k: [MTOT][256]; vT: [B][256][SEQ]
{
    __shared__ bf16 vt[64][72];
    const int lane = threadIdx.x & 63, wave = threadIdx.x >> 6;
    const int g = lane >> 4, c = lane & 15;
    const int mat = blockIdx.y >> 2;
    const int n0 = (blockIdx.y & 3) * 64;
    const int mblk = blockIdx.x * 64;
    const int m0 = mblk + wave * 16;
    const bf16* wT = (mat == 0) ? wqT : (mat == 1) ? wkT : wvT;
    const float* bias = (mat == 0) ? bq : (mat == 1) ? bk : bv;

    f32x4 acc[4] = {};
    #pragma unroll
    for (int ks = 0; ks < 8; ++ks) {
        bf16x8 a = *(const bf16x8*)(xb + (size_t)(m0 + c) * 256 + ks * 32 + 8 * g);
        #pragma unroll
        for (int nf = 0; nf < 4; ++nf) {
            bf16x8 b = *(const bf16x8*)(wT + (size_t)(n0 + nf * 16 + c) * 256 + ks * 32 + 8 * g);
            acc[nf] = MFMA_16x16x32(a, b, acc[nf]);
        }
    }
    if (mat < 2) {
        bf16* out = (mat == 0) ? q : k;
        #pragma unroll
        for (int nf = 0; nf < 4; ++nf) {
            int n = n0 + nf * 16 + c;
            float bs = bias[n];
            #pragma unroll
            for (int r = 0; r < 4; ++r)
                out[(size_t)(m0 + 4 * g + r) * 256 + n] = (bf16)(acc[nf][r] + bs);
        }
    } else {
        #pragma unroll
        for (int nf = 0; nf < 4; ++nf) {
            int n = n0 + nf * 16 + c;
            float bs = bias[n];
            #pragma unroll
            for (int r = 0; r < 4; ++r)
                vt[nf * 16 + c][wave * 16 + 4 * g + r] = (bf16)(acc[nf][r] + bs);
        }
        __syncthreads();
        int bt = mblk >> 12;        // /SEQ
        int s0 = mblk & (SEQ - 1);
        int nl = threadIdx.x >> 2;  // 0..63 -> col (n offset)
        int sc = (threadIdx.x & 3) * 16;  // row (s offset) chunk
        bf16* dst = vT + ((size_t)bt * 256 + n0 + nl) * SEQ + s0 + sc;
        const bf16x8* sp = (const bf16x8*)&vt[nl][sc];
        ((bf16x8*)dst)[0] = sp[0];
        ((bf16x8*)dst)[1] = sp[1];
    }
}

// ---------------- fused attention (flash, single-buffer 32KB LDS, swapped QK^T, KV-split x2) --
// (round-15/18 PASS version, byte-identical)

// chunk ch = i*256+tid; K: row=ch>>5, 16B-col=ch&31; V: d=ch>>2, s-chunk=ch&3.
#define STAGE_GLOAD(KV) do {                                                              \
    _Pragma("unroll")                                                                     \
    for (int i_ = 0; i_ < 4; ++i_) {                                                      \
        int ch_ = i_ * 256 + tid;                                                         \
        kreg[i_] = *(const bf16x8*)(kbase + (size_t)((KV) + (ch_ >> 5)) * 256 + (ch_ & 31) * 8); \
        vreg[i_] = *(const bf16x8*)(vbase + (size_t)(ch_ >> 2) * SEQ + (KV) + (ch_ & 3) * 8);    \
    } } while (0)

#define STAGE_DSWRITE() do {                                                              \
    _Pragma("unroll")                                                                     \
    for (int i_ = 0; i_ < 4; ++i_) {                                                      \
        int ch_ = i_ * 256 + tid;                                                         \
        int kr_ = ch_ >> 5, kcb_ = ch_ & 31;                                              \
        int kf_ = (kcb_ >> 2) * 2 + (kr_ >> 4);                                           \
        int kl_ = (kcb_ & 3) * 16 + (kr_ & 15);                                           \
        *(bf16x8*)&kstage[kf_][kl_ ^ ((kl_ >> 3) & 6)][0] = kreg[i_];                     \
        int vd_ = ch_ >> 2, vs_ = ch_ & 3;                                                \
        int g1_ = 2 * (vs_ & 1), jh_ = (vs_ >> 1) * 4;                                    \
        bf16x4 lo_ = ((const bf16x4*)&vreg[i_])[0];                                       \
        bf16x4 hi_ = ((const bf16x4*)&vreg[i_])[1];                                       \
        *(bf16x4*)&vstage[vd_ >> 4][g1_ * 16 + (vd_ & 15)][jh_]        = lo_;             \
        *(bf16x4*)&vstage[vd_ >> 4][g1_ * 16 + 16 + (vd_ & 15)][jh_]   = hi_;             \
    } } while (0)

#define ATTN_BODY() do {                                                                  \
    f32x4 s0 = {}, s1 = {};                                                               \
    __builtin_amdgcn_s_setprio(1);                                                        \
    _Pragma("unroll")                                                                     \
    for (int ks_ = 0; ks_ < 8; ++ks_) {                                                   \
        bf16x8 k0_ = *(const bf16x8*)&kstage[ks_ * 2 + 0][kln][0];                        \
        bf16x8 k1_ = *(const bf16x8*)&kstage[ks_ * 2 + 1][kln][0];                        \
        s0 = MFMA_16x16x32(k0_, qf[ks_], s0);                                             \
        s1 = MFMA_16x16x32(k1_, qf[ks_], s1);                                             \
    }                                                                                     \
    __builtin_amdgcn_s_setprio(0);                                                        \
    float p_[8];                                                                          \
    _Pragma("unroll")                                                                     \
    for (int r_ = 0; r_ < 4; ++r_) { p_[r_] = s0[r_] * 0.0625f; p_[4 + r_] = s1[r_] * 0.0625f; } \
    float mx = fmaxf(fmaxf(fmaxf(p_[0], p_[1]), fmaxf(p_[2], p_[3])),                     \
                     fmaxf(fmaxf(p_[4], p_[5]), fmaxf(p_[6], p_[7])));                    \
    mx = fmaxf(mx, __shfl_xor(mx, 16));                                                   \
    mx = fmaxf(mx, __shfl_xor(mx, 32));                                                   \
    if (__any(mx > m_run)) {   /* T13: rescale only when some row max grew */             \
        float mn = fmaxf(m_run, mx);                                                      \
        float a_ = __expf(m_run - mn);                                                    \
        m_run = mn; l_run *= a_;                                                          \
        float a0_ = __shfl(a_, 4 * g + 0), a1_ = __shfl(a_, 4 * g + 1);                   \
        float a2_ = __shfl(a_, 4 * g + 2), a3_ = __shfl(a_, 4 * g + 3);                   \
        _Pragma("unroll")                                                                 \
        for (int nf_ = 0; nf_ < 16; ++nf_) {                                              \
            o[nf_][0] *= a0_; o[nf_][1] *= a1_; o[nf_][2] *= a2_; o[nf_][3] *= a3_;       \
        }                                                                                 \
    }                                                                                     \
    float ls = 0.f;                                                                       \
    _Pragma("unroll")                                                                     \
    for (int j_ = 0; j_ < 8; ++j_) { p_[j_] = __expf(p_[j_] - m_run); ls += p_[j_]; }     \
    ls += __shfl_xor(ls, 16);                                                             \
    ls += __shfl_xor(ls, 32);                                                             \
    l_run += ls;                                                                          \
    bf16x8 pa;                                                                            \
    _Pragma("unroll")                                                                     \
    for (int j_ = 0; j_ < 8; ++j_) pa[j_] = (bf16)p_[j_];                                 \
    __builtin_amdgcn_s_setprio(1);                                                        \
    _Pragma("unroll")                                                                     \
    for (int nf_ = 0; nf_ < 16; ++nf_) {                                                  \
        bf16x8 v_ = *(const bf16x8*)&vstage[nf_][lane][0];                                \
        o[nf_] = MFMA_16x16x32(pa, v_, o[nf_]);                                           \
    }                                                                                     \
    __builtin_amdgcn_s_setprio(0);                                                        \
} while (0)

__global__ __launch_bounds__(256) void attn_kernel(
    const bf16* __restrict__ qb, const bf16* __restrict__ kb, const bf16* __restrict__ vT,
    float* __restrict__ o_part, float* __restrict__ ml_part)
{
    __shared__ bf16 kstage[16][64][8];   // 16 KB (single buffer)
    __shared__ bf16 vstage[16][64][8];   // 16 KB
    const int tid = threadIdx.x;
    const int lane = tid & 63, wave = tid >> 6;
    const int g = lane >> 4, c = lane & 15;
    const int kln = lane ^ ((lane >> 3) & 6);   // swizzled K read slot
    const int xcd = blockIdx.x & 7, qg = blockIdx.x >> 3;   // qg 0..63
    const int bt = xcd >> 1, split = xcd & 1;
    const int mrow = bt * SEQ + qg * 64 + wave * 16;
    const int kvS = split << 11;            // this block's KV half (2048 rows)

    bf16x8 qf[8];
    #pragma unroll
    for (int ks = 0; ks < 8; ++ks)
        qf[ks] = *(const bf16x8*)(qb + (size_t)(mrow + c) * 256 + ks * 32 + 8 * g);

    f32x4 o[16] = {};
    float m_run = -1e30f, l_run = 0.f;    // per-lane: softmax state for q-row = mrow + c

    const bf16* kbase = kb + (size_t)bt * SEQ * 256;
    const bf16* vbase = vT + (size_t)bt * 256 * SEQ;

    bf16x8 kreg[4], vreg[4];
    STAGE_GLOAD(kvS);
    STAGE_DSWRITE();
    __syncthreads();

    #pragma unroll 1
    for (int t = 0; t < 64; ++t) {
        if (t < 63) STAGE_GLOAD(kvS + (t + 1) * 32);   // issue early into regs (T14)
        ATTN_BODY();                                    // compute current tile from LDS
        __syncthreads();                                // all reads of stage done
        if (t < 63) {
            STAGE_DSWRITE();                            // overwrite with next tile
            __syncthreads();                            // writes visible to all waves
        }
    }

    // epilogue: normalized FP32 partial + (m,l) fp32
    float linv = 1.f / l_run;
    float l0 = __shfl(linv, 4 * g + 0), l1 = __shfl(linv, 4 * g + 1);
    float l2 = __shfl(linv, 4 * g + 2), l3 = __shfl(linv, 4 * g + 3);
    float* op = o_part + ((size_t)split * MTOT + mrow) * 256;
    #pragma unroll
    for (int nf = 0; nf < 16; ++nf) {
        op[(size_t)(4 * g + 0) * 256 + nf * 16 + c] = o[nf][0] * l0;
        op[(size_t)(4 * g + 1) * 256 + nf * 16 + c] = o[nf][1] * l1;
        op[(size_t)(4 * g + 2) * 256 + nf * 16 + c] = o[nf][2] * l2;
        op[(size_t)(4 * g + 3) * 256 + nf * 16 + c] = o[nf][3] * l3;
    }
    if (g == 0) {
        float2 ml = make_float2(m_run, l_run);
        *(float2*)&ml_part[((size_t)split * MTOT + mrow + c) * 2] = ml;
    }
}

// ---------------- Fused combine+FFN: y = LN(attn + relu(attn@w1+b1)@w2 + b2) ----------------
// grid MTOT/16 = 1024 blocks x 256 thr, h_lds 16KB (4 blocks/CU, r18-proven).
// Phase 0: flash-combine the 2 fp32 partials in registers.
//   r19 FAILED (absmax 1.016) with a shfl-broadcast of residual weights; this
//   version computes per-row weights DIRECTLY from ml_part (no cross-lane ops)
//   and rounds the residual through bf16 so the LN input is BIT-IDENTICAL to
//   the r18 PASS path (expected absmax exactly 0.015625 as a checksum).
// Phases 1/2 + LN epilogue = r18 PASS, byte-identical.
__global__ __launch_bounds__(256) void ffn_fused_kernel(
    const float* __restrict__ o_part, const float* __restrict__ ml_part,
    const bf16* __restrict__ w1T, const float* __restrict__ b1,
    const bf16* __restrict__ w2T, const float* __restrict__ b2,
    const float* __restrict__ ln_g, const float* __restrict__ ln_b,
    float* __restrict__ out)
{
    __shared__ bf16 h_lds[16][512];   // 16384 B
    const int lane = threadIdx.x & 63, wave = threadIdx.x >> 6;
    const int g = lane >> 4, c = lane & 15;
    const int m0 = blockIdx.x * 16;
    const int n2 = wave * 64;          // phase-2 output cols (fixed per wave)

    // ---- phase 0a: combine weights for row m0+c (own lane; feeds qa)
    float2 ml0 = *(const float2*)&ml_part[(size_t)(m0 + c) * 2];
    float2 ml1 = *(const float2*)&ml_part[((size_t)MTOT + m0 + c) * 2];
    float M = fmaxf(ml0.x, ml1.x);
    float wa = __expf(ml0.x - M) * ml0.y;
    float wb = __expf(ml1.x - M) * ml1.y;
    float Li = 1.f / (wa + wb);
    wa *= Li; wb *= Li;

    // qa frags: combined attn row m0+c (bf16 values == old attn_bf)
    const float* op0 = o_part + (size_t)(m0 + c) * 256;
    const float* op1 = o_part + ((size_t)MTOT + m0 + c) * 256;
    bf16x8 qa[8];
    #pragma unroll
    for (int ks = 0; ks < 8; ++ks) {
        int off = ks * 32 + 8 * g;
        float4 a0 = *(const float4*)(op0 + off);
        float4 a1 = *(const float4*)(op0 + off + 4);
        float4 c0 = *(const float4*)(op1 + off);
        float4 c1 = *(const float4*)(op1 + off + 4);
        qa[ks][0] = (bf16)(wa * a0.x + wb * c0.x);
        qa[ks][1] = (bf16)(wa * a0.y + wb * c0.y);
        qa[ks][2] = (bf16)(wa * a0.z + wb * c0.z);
        qa[ks][3] = (bf16)(wa * a0.w + wb * c0.w);
        qa[ks][4] = (bf16)(wa * a1.x + wb * c1.x);
        qa[ks][5] = (bf16)(wa * a1.y + wb * c1.y);
        qa[ks][6] = (bf16)(wa * a1.z + wb * c1.z);
        qa[ks][7] = (bf16)(wa * a1.w + wb * c1.w);
    }

    // ---- phase 0b: residual for rows m0+4g+r at this wave's cols.
    // Per-row weights computed DIRECTLY (no shfl); residual bf16-rounded.
    float w0r[4], w1r[4];
    #pragma unroll
    for (int r = 0; r < 4; ++r) {
        float2 mla = *(const float2*)&ml_part[(size_t)(m0 + 4 * g + r) * 2];
        float2 mlb = *(const float2*)&ml_part[((size_t)MTOT + m0 + 4 * g + r) * 2];
        float Mr = fmaxf(mla.x, mlb.x);
        float u0 = __expf(mla.x - Mr) * mla.y;
        float u1 = __expf(mlb.x - Mr) * mlb.y;
        float Lr = 1.f / (u0 + u1);
        w0r[r] = u0 * Lr; w1r[r] = u1 * Lr;
    }
    float res[4][4];
    #pragma unroll
    for (int nf = 0; nf < 4; ++nf) {
        int col = n2 + nf * 16 + c;
        #pragma unroll
        for (int r = 0; r < 4; ++r) {
            float v0 = o_part[(size_t)(m0 + 4 * g + r) * 256 + col];
            float v1 = o_part[((size_t)MTOT + m0 + 4 * g + r) * 256 + col];
            res[nf][r] = (float)(bf16)(w0r[r] * v0 + w1r[r] * v1);
        }
    }

    f32x4 acc2[4] = {};
    #pragma unroll 1
    for (int half = 0; half < 2; ++half) {
        // ---- phase 1: h cols [half*512 + wave*128, +128) for all 16 rows
        const int n1 = half * 512 + wave * 128;
        f32x4 acc1[8] = {};
        #pragma unroll
        for (int ks = 0; ks < 8; ++ks) {
            #pragma unroll
            for (int nf = 0; nf < 8; ++nf) {
                bf16x8 b = *(const bf16x8*)(w1T + (size_t)(n1 + nf * 16 + c) * 256 + ks * 32 + 8 * g);
                acc1[nf] = MFMA_16x16x32(qa[ks], b, acc1[nf]);
            }
        }
        #pragma unroll
        for (int nf = 0; nf < 8; ++nf) {
            int nl = wave * 128 + nf * 16 + c;      // local col within half (0..511)
            float bs = b1[half * 512 + nl];
            int chunk = nl >> 3, off = nl & 7;
            #pragma unroll
            for (int r = 0; r < 4; ++r) {
                int row = 4 * g + r;
                h_lds[row][((chunk ^ (row & 7)) << 3) | off] = (bf16)fmaxf(acc1[nf][r] + bs, 0.f);
            }
        }
        __syncthreads();
        // ---- phase 2: acc2 += h(half) @ w2(half rows), K = 512
        #pragma unroll 4
        for (int ks = 0; ks < 16; ++ks) {
            int chunk = 4 * ks + g;
            bf16x8 a = *(const bf16x8*)&h_lds[c][(chunk ^ (c & 7)) << 3];
            #pragma unroll
            for (int nf = 0; nf < 4; ++nf) {
                bf16x8 b = *(const bf16x8*)(w2T + (size_t)(n2 + nf * 16 + c) * 1024 + half * 512 + ks * 32 + 8 * g);
                acc2[nf] = MFMA_16x16x32(a, b, acc2[nf]);
            }
        }
        __syncthreads();   // phase-2 reads done before next half overwrites
    }

    // residual + bias; per-wave LN partial sums over its 64 cols
    float sum[4] = {}, sq[4] = {};
    #pragma unroll
    for (int nf = 0; nf < 4; ++nf) {
        int col = n2 + nf * 16 + c;
        float bs = b2[col];
        #pragma unroll
        for (int r = 0; r < 4; ++r) {
            float v = acc2[nf][r] + bs + res[nf][r];
            acc2[nf][r] = v;
            sum[r] += v; sq[r] += v * v;
        }
    }
    #pragma unroll
    for (int r = 0; r < 4; ++r) {
        sum[r] += __shfl_xor(sum[r], 1); sum[r] += __shfl_xor(sum[r], 2);
        sum[r] += __shfl_xor(sum[r], 4); sum[r] += __shfl_xor(sum[r], 8);
        sq[r]  += __shfl_xor(sq[r], 1);  sq[r]  += __shfl_xor(sq[r], 2);
        sq[r]  += __shfl_xor(sq[r], 4);  sq[r]  += __shfl_xor(sq[r], 8);
    }
    // cross-wave merge via dead h_lds: sums[wave][row][2]
    float* sums = (float*)&h_lds[0][0];
    if (c == 0) {
        #pragma unroll
        for (int r = 0; r < 4; ++r) {
            sums[wave * 32 + (4 * g + r) * 2 + 0] = sum[r];
            sums[wave * 32 + (4 * g + r) * 2 + 1] = sq[r];
        }
    }
    __syncthreads();
    #pragma unroll
    for (int r = 0; r < 4; ++r) {
        int row = 4 * g + r;
        float S = sums[0 * 32 + row * 2] + sums[1 * 32 + row * 2]
                + sums[2 * 32 + row * 2] + sums[3 * 32 + row * 2];
        float Q = sums[0 * 32 + row * 2 + 1] + sums[1 * 32 + row * 2 + 1]
                + sums[2 * 32 + row * 2 + 1] + sums[3 * 32 + row * 2 + 1];
        float mean = S * (1.f / 256.f);
        float rstd = rsqrtf(Q * (1.f / 256.f) - mean * mean + 1e-5f);
        #pragma unroll
        for (int nf = 0; nf < 4; ++nf) {
            int col = n2 + nf * 16 + c;
            out[(size_t)(m0 + row) * 256 + col] = (acc2[nf][r] - mean) * rstd * ln_g[col] + ln_b[col];
        }
    }
}

// ---------------- launch ----------------
// ws layout (bytes), ~69.5 MB total (round-13..18 proved this range valid):
//   0        weights (1.44MB)
//   2097152  xb (8M)
//   10485760 qb (8M)
//   18874368 kb (8M)
//   27262976 vT (8M)
//   35651584 o_part f32 [2][MTOT][256] (32M)   WRITE-ONCE (attn), READ-ONCE (ffn)
//   69206016 ml_part f32 [2][MTOT][2] (256K)   [end 69468160]
extern "C" void kernel_launch(void* const* d_in, const int* in_sizes, int n_in,
                              void* d_out, int out_size, void* d_ws, size_t ws_size,
                              hipStream_t stream) {
    const float* x    = (const float*)d_in[0];
    const float* wq   = (const float*)d_in[1];
    const float* bq   = (const float*)d_in[2];
    const float* wk   = (const float*)d_in[3];
    const float* bk   = (const float*)d_in[4];
    const float* wv   = (const float*)d_in[5];
    const float* bv   = (const float*)d_in[6];
    const float* w1   = (const float*)d_in[7];
    const float* b1   = (const float*)d_in[8];
    const float* w2   = (const float*)d_in[9];
    const float* b2   = (const float*)d_in[10];
    const float* ln_g = (const float*)d_in[11];
    const float* ln_b = (const float*)d_in[12];
    float* out = (float*)d_out;   // fp32 output

    char* ws = (char*)d_ws;
    bf16* wqT = (bf16*)(ws + 0);
    bf16* wkT = (bf16*)(ws + 131072);
    bf16* wvT = (bf16*)(ws + 262144);
    bf16* w1T = (bf16*)(ws + 393216);
    bf16* w2T = (bf16*)(ws + 917504);
    bf16* xb  = (bf16*)(ws + 2097152);
    bf16* qb  = (bf16*)(ws + 10485760);
    bf16* kb  = (bf16*)(ws + 18874368);
    bf16* vT  = (bf16*)(ws + 27262976);
    float* o_part  = (float*)(ws + 35651584);
    float* ml_part = (float*)(ws + 69206016);

    const int PREP_N = (1048576 + 3 * 65536 + 2 * 262144) / 256;   // 6912 blocks
    prep_kernel<<<PREP_N, 256, 0, stream>>>(x, wq, wk, wv, w1, w2, xb, wqT, wkT, wvT, w1T, w2T);

    qkv_kernel<<<dim3(MTOT / 64, 12), 256, 0, stream>>>(xb, wqT, wkT, wvT, bq, bk, bv, qb, kb, vT);
    attn_kernel<<<(MTOT / 64) * NSPLIT, 256, 0, stream>>>(qb, kb, vT, o_part, ml_part);
    ffn_fused_kernel<<<MTOT / 16, 256, 0, stream>>>(o_part, ml_part, w1T, b1, w2T, b2, ln_g, ln_b, out);
}

// Round 22
// 313.926 us; speedup vs baseline: 1.0783x; 1.0783x over previous
//
#include <hip/hip_runtime.h>
#include <hip/hip_bf16.h>

typedef __bf16 bf16;
typedef __attribute__((ext_vector_type(8))) __bf16 bf16x8;
typedef __attribute__((ext_vector_type(4))) __bf16 bf16x4;
typedef __attribute__((ext_vector_type(4))) float f32x4;

#define MFMA_16x16x32(a, b, c) __builtin_amdgcn_mfma_f32_16x16x32_bf16(a, b, c, 0, 0, 0)

// Problem dims (fixed by the reference)
#define BATCH 4
#define SEQ   4096
#define HID   256
#define FFD   1024
#define MTOT  (BATCH * SEQ)   // 16384
#define NSPLIT 2              // KV splits per q-group (fp32 partials)

// ---------------- fused prep kernel (cast x + 5 weight transposes, 1 launch) ----------------
__global__ __launch_bounds__(256) void prep_kernel(
    const float* __restrict__ x,
    const float* __restrict__ wq, const float* __restrict__ wk, const float* __restrict__ wv,
    const float* __restrict__ w1, const float* __restrict__ w2,
    bf16* __restrict__ xb,
    bf16* __restrict__ wqT, bf16* __restrict__ wkT, bf16* __restrict__ wvT,
    bf16* __restrict__ w1T, bf16* __restrict__ w2T)
{
    int i = blockIdx.x * 256 + threadIdx.x;
    if (i < 1048576) {
        float4 v = ((const float4*)x)[i];
        bf16x4 o;
        o[0] = (bf16)v.x; o[1] = (bf16)v.y; o[2] = (bf16)v.z; o[3] = (bf16)v.w;
        ((bf16x4*)xb)[i] = o;
        return;
    }
    i -= 1048576;
    if (i < 3 * 65536) {
        const float* src = (i < 65536) ? wq : (i < 131072) ? wk : wv;
        bf16* dst = (i < 65536) ? wqT : (i < 131072) ? wkT : wvT;
        int j = i & 65535;
        int r = j >> 8, c = j & 255;
        dst[c * 256 + r] = (bf16)src[j];
        return;
    }
    i -= 3 * 65536;
    if (i < 262144) {                 // w1: [256][1024] -> w1T [1024][256]
        int r = i >> 10, c = i & 1023;
        w1T[c * 256 + r] = (bf16)w1[i];
        return;
    }
    i -= 262144;                      // w2: [1024][256] -> w2T [256][1024]
    int r = i >> 8, c = i & 255;
    w2T[c * 1024 + r] = (bf16)w2[i];
}

// ---------------- QKV projection ----------------
// grid (MTOT/64, 12); blockIdx.y: 0-3 -> q cols, 4-7 -> k cols, 8-11 -> v cols
__global__ __launch_bounds__(256) void qkv_kernel(
    const bf16* __restrict__ xb,                       // [MTOT][256]
    const bf16* __restrict__ wqT, const bf16* __restrict__ wkT, const bf16* __restrict__ wvT,
    const float* __restrict__ bq, const float* __restrict__ bk, const float* __restrict__ bv,
    bf16* __restrict__ q, bf16* __restrict__ k, bf16* __restrict__ vT) // q,k: [MTOT][256]; vT: [B][256][SEQ]
{
    __shared__ bf16 vt[64][72];
    const int lane = threadIdx.x & 63, wave = threadIdx.x >> 6;
    const int g = lane >> 4, c = lane & 15;
    const int mat = blockIdx.y >> 2;
    const int n0 = (blockIdx.y & 3) * 64;
    const int mblk = blockIdx.x * 64;
    const int m0 = mblk + wave * 16;
    const bf16* wT = (mat == 0) ? wqT : (mat == 1) ? wkT : wvT;
    const float* bias = (mat == 0) ? bq : (mat == 1) ? bk : bv;

    f32x4 acc[4] = {};
    #pragma unroll
    for (int ks = 0; ks < 8; ++ks) {
        bf16x8 a = *(const bf16x8*)(xb + (size_t)(m0 + c) * 256 + ks * 32 + 8 * g);
        #pragma unroll
        for (int nf = 0; nf < 4; ++nf) {
            bf16x8 b = *(const bf16x8*)(wT + (size_t)(n0 + nf * 16 + c) * 256 + ks * 32 + 8 * g);
            acc[nf] = MFMA_16x16x32(a, b, acc[nf]);
        }
    }
    if (mat < 2) {
        bf16* out = (mat == 0) ? q : k;
        #pragma unroll
        for (int nf = 0; nf < 4; ++nf) {
            int n = n0 + nf * 16 + c;
            float bs = bias[n];
            #pragma unroll
            for (int r = 0; r < 4; ++r)
                out[(size_t)(m0 + 4 * g + r) * 256 + n] = (bf16)(acc[nf][r] + bs);
        }
    } else {
        #pragma unroll
        for (int nf = 0; nf < 4; ++nf) {
            int n = n0 + nf * 16 + c;
            float bs = bias[n];
            #pragma unroll
            for (int r = 0; r < 4; ++r)
                vt[nf * 16 + c][wave * 16 + 4 * g + r] = (bf16)(acc[nf][r] + bs);
        }
        __syncthreads();
        int bt = mblk >> 12;        // /SEQ
        int s0 = mblk & (SEQ - 1);
        int nl = threadIdx.x >> 2;  // 0..63 -> col (n offset)
        int sc = (threadIdx.x & 3) * 16;  // row (s offset) chunk
        bf16* dst = vT + ((size_t)bt * 256 + n0 + nl) * SEQ + s0 + sc;
        const bf16x8* sp = (const bf16x8*)&vt[nl][sc];
        ((bf16x8*)dst)[0] = sp[0];
        ((bf16x8*)dst)[1] = sp[1];
    }
}

// ---------------- fused attention (flash, single-buffer 32KB LDS, swapped QK^T, KV-split x2) --
// (round-15/18 PASS version; only change this round: __launch_bounds__(256,2))

// chunk ch = i*256+tid; K: row=ch>>5, 16B-col=ch&31; V: d=ch>>2, s-chunk=ch&3.
#define STAGE_GLOAD(KV) do {                                                              \
    _Pragma("unroll")                                                                     \
    for (int i_ = 0; i_ < 4; ++i_) {                                                      \
        int ch_ = i_ * 256 + tid;                                                         \
        kreg[i_] = *(const bf16x8*)(kbase + (size_t)((KV) + (ch_ >> 5)) * 256 + (ch_ & 31) * 8); \
        vreg[i_] = *(const bf16x8*)(vbase + (size_t)(ch_ >> 2) * SEQ + (KV) + (ch_ & 3) * 8);    \
    } } while (0)

#define STAGE_DSWRITE() do {                                                              \
    _Pragma("unroll")                                                                     \
    for (int i_ = 0; i_ < 4; ++i_) {                                                      \
        int ch_ = i_ * 256 + tid;                                                         \
        int kr_ = ch_ >> 5, kcb_ = ch_ & 31;                                              \
        int kf_ = (kcb_ >> 2) * 2 + (kr_ >> 4);                                           \
        int kl_ = (kcb_ & 3) * 16 + (kr_ & 15);                                           \
        *(bf16x8*)&kstage[kf_][kl_ ^ ((kl_ >> 3) & 6)][0] = kreg[i_];                     \
        int vd_ = ch_ >> 2, vs_ = ch_ & 3;                                                \
        int g1_ = 2 * (vs_ & 1), jh_ = (vs_ >> 1) * 4;                                    \
        bf16x4 lo_ = ((const bf16x4*)&vreg[i_])[0];                                       \
        bf16x4 hi_ = ((const bf16x4*)&vreg[i_])[1];                                       \
        *(bf16x4*)&vstage[vd_ >> 4][g1_ * 16 + (vd_ & 15)][jh_]        = lo_;             \
        *(bf16x4*)&vstage[vd_ >> 4][g1_ * 16 + 16 + (vd_ & 15)][jh_]   = hi_;             \
    } } while (0)

#define ATTN_BODY() do {                                                                  \
    f32x4 s0 = {}, s1 = {};                                                               \
    __builtin_amdgcn_s_setprio(1);                                                        \
    _Pragma("unroll")                                                                     \
    for (int ks_ = 0; ks_ < 8; ++ks_) {                                                   \
        bf16x8 k0_ = *(const bf16x8*)&kstage[ks_ * 2 + 0][kln][0];                        \
        bf16x8 k1_ = *(const bf16x8*)&kstage[ks_ * 2 + 1][kln][0];                        \
        s0 = MFMA_16x16x32(k0_, qf[ks_], s0);                                             \
        s1 = MFMA_16x16x32(k1_, qf[ks_], s1);                                             \
    }                                                                                     \
    __builtin_amdgcn_s_setprio(0);                                                        \
    float p_[8];                                                                          \
    _Pragma("unroll")                                                                     \
    for (int r_ = 0; r_ < 4; ++r_) { p_[r_] = s0[r_] * 0.0625f; p_[4 + r_] = s1[r_] * 0.0625f; } \
    float mx = fmaxf(fmaxf(fmaxf(p_[0], p_[1]), fmaxf(p_[2], p_[3])),                     \
                     fmaxf(fmaxf(p_[4], p_[5]), fmaxf(p_[6], p_[7])));                    \
    mx = fmaxf(mx, __shfl_xor(mx, 16));                                                   \
    mx = fmaxf(mx, __shfl_xor(mx, 32));                                                   \
    if (__any(mx > m_run)) {   /* T13: rescale only when some row max grew */             \
        float mn = fmaxf(m_run, mx);                                                      \
        float a_ = __expf(m_run - mn);                                                    \
        m_run = mn; l_run *= a_;                                                          \
        float a0_ = __shfl(a_, 4 * g + 0), a1_ = __shfl(a_, 4 * g + 1);                   \
        float a2_ = __shfl(a_, 4 * g + 2), a3_ = __shfl(a_, 4 * g + 3);                   \
        _Pragma("unroll")                                                                 \
        for (int nf_ = 0; nf_ < 16; ++nf_) {                                              \
            o[nf_][0] *= a0_; o[nf_][1] *= a1_; o[nf_][2] *= a2_; o[nf_][3] *= a3_;       \
        }                                                                                 \
    }                                                                                     \
    float ls = 0.f;                                                                       \
    _Pragma("unroll")                                                                     \
    for (int j_ = 0; j_ < 8; ++j_) { p_[j_] = __expf(p_[j_] - m_run); ls += p_[j_]; }     \
    ls += __shfl_xor(ls, 16);                                                             \
    ls += __shfl_xor(ls, 32);                                                             \
    l_run += ls;                                                                          \
    bf16x8 pa;                                                                            \
    _Pragma("unroll")                                                                     \
    for (int j_ = 0; j_ < 8; ++j_) pa[j_] = (bf16)p_[j_];                                 \
    __builtin_amdgcn_s_setprio(1);                                                        \
    _Pragma("unroll")                                                                     \
    for (int nf_ = 0; nf_ < 16; ++nf_) {                                                  \
        bf16x8 v_ = *(const bf16x8*)&vstage[nf_][lane][0];                                \
        o[nf_] = MFMA_16x16x32(pa, v_, o[nf_]);                                           \
    }                                                                                     \
    __builtin_amdgcn_s_setprio(0);                                                        \
} while (0)

__global__ __launch_bounds__(256, 2) void attn_kernel(
    const bf16* __restrict__ qb, const bf16* __restrict__ kb, const bf16* __restrict__ vT,
    float* __restrict__ o_part, float* __restrict__ ml_part)
{
    __shared__ bf16 kstage[16][64][8];   // 16 KB (single buffer)
    __shared__ bf16 vstage[16][64][8];   // 16 KB
    const int tid = threadIdx.x;
    const int lane = tid & 63, wave = tid >> 6;
    const int g = lane >> 4, c = lane & 15;
    const int kln = lane ^ ((lane >> 3) & 6);   // swizzled K read slot
    const int xcd = blockIdx.x & 7, qg = blockIdx.x >> 3;   // qg 0..63
    const int bt = xcd >> 1, split = xcd & 1;
    const int mrow = bt * SEQ + qg * 64 + wave * 16;
    const int kvS = split << 11;            // this block's KV half (2048 rows)

    bf16x8 qf[8];
    #pragma unroll
    for (int ks = 0; ks < 8; ++ks)
        qf[ks] = *(const bf16x8*)(qb + (size_t)(mrow + c) * 256 + ks * 32 + 8 * g);

    f32x4 o[16] = {};
    float m_run = -1e30f, l_run = 0.f;    // per-lane: softmax state for q-row = mrow + c

    const bf16* kbase = kb + (size_t)bt * SEQ * 256;
    const bf16* vbase = vT + (size_t)bt * 256 * SEQ;

    bf16x8 kreg[4], vreg[4];
    STAGE_GLOAD(kvS);
    STAGE_DSWRITE();
    __syncthreads();

    #pragma unroll 1
    for (int t = 0; t < 64; ++t) {
        if (t < 63) STAGE_GLOAD(kvS + (t + 1) * 32);   // issue early into regs (T14)
        ATTN_BODY();                                    // compute current tile from LDS
        __syncthreads();                                // all reads of stage done
        if (t < 63) {
            STAGE_DSWRITE();                            // overwrite with next tile
            __syncthreads();                            // writes visible to all waves
        }
    }

    // epilogue: normalized FP32 partial + (m,l) fp32
    float linv = 1.f / l_run;
    float l0 = __shfl(linv, 4 * g + 0), l1 = __shfl(linv, 4 * g + 1);
    float l2 = __shfl(linv, 4 * g + 2), l3 = __shfl(linv, 4 * g + 3);
    float* op = o_part + ((size_t)split * MTOT + mrow) * 256;
    #pragma unroll
    for (int nf = 0; nf < 16; ++nf) {
        op[(size_t)(4 * g + 0) * 256 + nf * 16 + c] = o[nf][0] * l0;
        op[(size_t)(4 * g + 1) * 256 + nf * 16 + c] = o[nf][1] * l1;
        op[(size_t)(4 * g + 2) * 256 + nf * 16 + c] = o[nf][2] * l2;
        op[(size_t)(4 * g + 3) * 256 + nf * 16 + c] = o[nf][3] * l3;
    }
    if (g == 0) {
        float2 ml = make_float2(m_run, l_run);
        *(float2*)&ml_part[((size_t)split * MTOT + mrow + c) * 2] = ml;
    }
}

// ---------------- attention combine (flash merge of 2 normalized fp32 partials) ----------
__global__ __launch_bounds__(256) void attn_combine_kernel(
    const float* __restrict__ o_part, const float* __restrict__ ml_part,
    bf16* __restrict__ attn_bf)
{
    const int row = blockIdx.x * 16 + (threadIdx.x >> 4);
    const int c0 = (threadIdx.x & 15) * 16;
    float m[NSPLIT], l[NSPLIT];
    #pragma unroll
    for (int s = 0; s < NSPLIT; ++s) {
        float2 ml = *(const float2*)&ml_part[((size_t)s * MTOT + row) * 2];
        m[s] = ml.x; l[s] = ml.y;
    }
    float M = fmaxf(m[0], m[1]);
    float w[NSPLIT], L = 0.f;
    #pragma unroll
    for (int s = 0; s < NSPLIT; ++s) { w[s] = __expf(m[s] - M) * l[s]; L += w[s]; }
    float Linv = 1.f / L;
    #pragma unroll
    for (int s = 0; s < NSPLIT; ++s) w[s] *= Linv;

    float acc[16] = {};
    #pragma unroll
    for (int s = 0; s < NSPLIT; ++s) {
        const float* op = o_part + ((size_t)s * MTOT + row) * 256 + c0;
        #pragma unroll
        for (int j4 = 0; j4 < 4; ++j4) {
            float4 v = ((const float4*)op)[j4];
            acc[j4 * 4 + 0] += w[s] * v.x; acc[j4 * 4 + 1] += w[s] * v.y;
            acc[j4 * 4 + 2] += w[s] * v.z; acc[j4 * 4 + 3] += w[s] * v.w;
        }
    }
    bf16* dst = attn_bf + (size_t)row * 256 + c0;
    #pragma unroll
    for (int j = 0; j < 16; ++j) dst[j] = (bf16)acc[j];
}

// ---------------- Fused FFN: y = LN(attn + relu(attn@w1+b1)@w2 + b2) ----------------
// grid MTOT/16 = 1024 blocks x 256 thr. Block = 16 rows. Two 512-col halves ->
// h_lds 16KB -> 4 blocks/CU (r18 PASS config). Only change: __launch_bounds__(256,2).
__global__ __launch_bounds__(256, 2) void ffn_fused_kernel(
    const bf16* __restrict__ attn, const bf16* __restrict__ w1T, const float* __restrict__ b1,
    const bf16* __restrict__ w2T, const float* __restrict__ b2,
    const float* __restrict__ ln_g, const float* __restrict__ ln_b,
    float* __restrict__ out)
{
    __shared__ bf16 h_lds[16][512];   // 16384 B
    const int lane = threadIdx.x & 63, wave = threadIdx.x >> 6;
    const int g = lane >> 4, c = lane & 15;
    const int m0 = blockIdx.x * 16;

    // attn rows (phase-1 A operand), hoisted across halves
    bf16x8 qa[8];
    #pragma unroll
    for (int ks = 0; ks < 8; ++ks)
        qa[ks] = *(const bf16x8*)(attn + (size_t)(m0 + c) * 256 + ks * 32 + 8 * g);

    const int n2 = wave * 64;          // phase-2 output cols (fixed per wave)
    f32x4 acc2[4] = {};

    #pragma unroll 1
    for (int half = 0; half < 2; ++half) {
        // ---- phase 1: h cols [half*512 + wave*128, +128) for all 16 rows
        const int n1 = half * 512 + wave * 128;
        f32x4 acc1[8] = {};
        #pragma unroll
        for (int ks = 0; ks < 8; ++ks) {
            #pragma unroll
            for (int nf = 0; nf < 8; ++nf) {
                bf16x8 b = *(const bf16x8*)(w1T + (size_t)(n1 + nf * 16 + c) * 256 + ks * 32 + 8 * g);
                acc1[nf] = MFMA_16x16x32(qa[ks], b, acc1[nf]);
            }
        }
        #pragma unroll
        for (int nf = 0; nf < 8; ++nf) {
            int nl = wave * 128 + nf * 16 + c;      // local col within half (0..511)
            float bs = b1[half * 512 + nl];
            int chunk = nl >> 3, off = nl & 7;
            #pragma unroll
            for (int r = 0; r < 4; ++r) {
                int row = 4 * g + r;
                h_lds[row][((chunk ^ (row & 7)) << 3) | off] = (bf16)fmaxf(acc1[nf][r] + bs, 0.f);
            }
        }
        __syncthreads();
        // ---- phase 2: acc2 += h(half) @ w2(half rows), K = 512
        #pragma unroll 4
        for (int ks = 0; ks < 16; ++ks) {
            int chunk = 4 * ks + g;
            bf16x8 a = *(const bf16x8*)&h_lds[c][(chunk ^ (c & 7)) << 3];
            #pragma unroll
            for (int nf = 0; nf < 4; ++nf) {
                bf16x8 b = *(const bf16x8*)(w2T + (size_t)(n2 + nf * 16 + c) * 1024 + half * 512 + ks * 32 + 8 * g);
                acc2[nf] = MFMA_16x16x32(a, b, acc2[nf]);
            }
        }
        __syncthreads();   // phase-2 reads done before next half overwrites
    }

    // residual + bias; per-wave LN partial sums over its 64 cols
    float sum[4] = {}, sq[4] = {};
    #pragma unroll
    for (int nf = 0; nf < 4; ++nf) {
        int col = n2 + nf * 16 + c;
        float bs = b2[col];
        #pragma unroll
        for (int r = 0; r < 4; ++r) {
            float v = acc2[nf][r] + bs + (float)attn[(size_t)(m0 + 4 * g + r) * 256 + col];
            acc2[nf][r] = v;
            sum[r] += v; sq[r] += v * v;
        }
    }
    #pragma unroll
    for (int r = 0; r < 4; ++r) {
        sum[r] += __shfl_xor(sum[r], 1); sum[r] += __shfl_xor(sum[r], 2);
        sum[r] += __shfl_xor(sum[r], 4); sum[r] += __shfl_xor(sum[r], 8);
        sq[r]  += __shfl_xor(sq[r], 1);  sq[r]  += __shfl_xor(sq[r], 2);
        sq[r]  += __shfl_xor(sq[r], 4);  sq[r]  += __shfl_xor(sq[r], 8);
    }
    // cross-wave merge via dead h_lds: sums[wave][row][2]
    float* sums = (float*)&h_lds[0][0];
    if (c == 0) {
        #pragma unroll
        for (int r = 0; r < 4; ++r) {
            sums[wave * 32 + (4 * g + r) * 2 + 0] = sum[r];
            sums[wave * 32 + (4 * g + r) * 2 + 1] = sq[r];
        }
    }
    __syncthreads();
    #pragma unroll
    for (int r = 0; r < 4; ++r) {
        int row = 4 * g + r;
        float S = sums[0 * 32 + row * 2] + sums[1 * 32 + row * 2]
                + sums[2 * 32 + row * 2] + sums[3 * 32 + row * 2];
        float Q = sums[0 * 32 + row * 2 + 1] + sums[1 * 32 + row * 2 + 1]
                + sums[2 * 32 + row * 2 + 1] + sums[3 * 32 + row * 2 + 1];
        float mean = S * (1.f / 256.f);
        float rstd = rsqrtf(Q * (1.f / 256.f) - mean * mean + 1e-5f);
        #pragma unroll
        for (int nf = 0; nf < 4; ++nf) {
            int col = n2 + nf * 16 + c;
            out[(size_t)(m0 + row) * 256 + col] = (acc2[nf][r] - mean) * rstd * ln_g[col] + ln_b[col];
        }
    }
}

// ---------------- launch ----------------
// ws layout (bytes), ~69.5 MB total (round-13..20 proved this range valid):
//   0        weights (1.44MB)
//   2097152  xb (8M)  -> attn_bf after combine
//   10485760 qb (8M)
//   18874368 kb (8M)
//   27262976 vT (8M)
//   35651584 o_part f32 [2][MTOT][256] (32M)   WRITE-ONCE, READ-ONCE, never reused
//   69206016 ml_part f32 [2][MTOT][2] (256K)   [end 69468160]
extern "C" void kernel_launch(void* const* d_in, const int* in_sizes, int n_in,
                              void* d_out, int out_size, void* d_ws, size_t ws_size,
                              hipStream_t stream) {
    const float* x    = (const float*)d_in[0];
    const float* wq   = (const float*)d_in[1];
    const float* bq   = (const float*)d_in[2];
    const float* wk   = (const float*)d_in[3];
    const float* bk   = (const float*)d_in[4];
    const float* wv   = (const float*)d_in[5];
    const float* bv   = (const float*)d_in[6];
    const float* w1   = (const float*)d_in[7];
    const float* b1   = (const float*)d_in[8];
    const float* w2   = (const float*)d_in[9];
    const float* b2   = (const float*)d_in[10];
    const float* ln_g = (const float*)d_in[11];
    const float* ln_b = (const float*)d_in[12];
    float* out = (float*)d_out;   // fp32 output

    char* ws = (char*)d_ws;
    bf16* wqT = (bf16*)(ws + 0);
    bf16* wkT = (bf16*)(ws + 131072);
    bf16* wvT = (bf16*)(ws + 262144);
    bf16* w1T = (bf16*)(ws + 393216);
    bf16* w2T = (bf16*)(ws + 917504);
    bf16* xb  = (bf16*)(ws + 2097152);
    bf16* qb  = (bf16*)(ws + 10485760);
    bf16* kb  = (bf16*)(ws + 18874368);
    bf16* vT  = (bf16*)(ws + 27262976);
    float* o_part  = (float*)(ws + 35651584);
    float* ml_part = (float*)(ws + 69206016);
    bf16* attn_bf = xb;   // xb dead after qkv

    const int PREP_N = (1048576 + 3 * 65536 + 2 * 262144) / 256;   // 6912 blocks
    prep_kernel<<<PREP_N, 256, 0, stream>>>(x, wq, wk, wv, w1, w2, xb, wqT, wkT, wvT, w1T, w2T);

    qkv_kernel<<<dim3(MTOT / 64, 12), 256, 0, stream>>>(xb, wqT, wkT, wvT, bq, bk, bv, qb, kb, vT);
    attn_kernel<<<(MTOT / 64) * NSPLIT, 256, 0, stream>>>(qb, kb, vT, o_part, ml_part);
    attn_combine_kernel<<<MTOT / 16, 256, 0, stream>>>(o_part, ml_part, attn_bf);
    ffn_fused_kernel<<<MTOT / 16, 256, 0, stream>>>(attn_bf, w1T, b1, w2T, b2, ln_g, ln_b, out);
}

// Round 23
// 313.337 us; speedup vs baseline: 1.0803x; 1.0019x over previous
//
#include <hip/hip_runtime.h>
#include <hip/hip_bf16.h>

typedef __bf16 bf16;
typedef __attribute__((ext_vector_type(8))) __bf16 bf16x8;
typedef __attribute__((ext_vector_type(4))) __bf16 bf16x4;
typedef __attribute__((ext_vector_type(4))) float f32x4;

#define MFMA_16x16x32(a, b, c) __builtin_amdgcn_mfma_f32_16x16x32_bf16(a, b, c, 0, 0, 0)

// Problem dims (fixed by the reference)
#define BATCH 4
#define SEQ   4096
#define HID   256
#define FFD   1024
#define MTOT  (BATCH * SEQ)   // 16384
#define NSPLIT 2              // KV splits per q-group (fp32 partials)

// ---------------- fused prep kernel (cast x + 5 weight transposes, 1 launch) ----------------
__global__ __launch_bounds__(256) void prep_kernel(
    const float* __restrict__ x,
    const float* __restrict__ wq, const float* __restrict__ wk, const float* __restrict__ wv,
    const float* __restrict__ w1, const float* __restrict__ w2,
    bf16* __restrict__ xb,
    bf16* __restrict__ wqT, bf16* __restrict__ wkT, bf16* __restrict__ wvT,
    bf16* __restrict__ w1T, bf16* __restrict__ w2T)
{
    int i = blockIdx.x * 256 + threadIdx.x;
    if (i < 1048576) {
        float4 v = ((const float4*)x)[i];
        bf16x4 o;
        o[0] = (bf16)v.x; o[1] = (bf16)v.y; o[2] = (bf16)v.z; o[3] = (bf16)v.w;
        ((bf16x4*)xb)[i] = o;
        return;
    }
    i -= 1048576;
    if (i < 3 * 65536) {
        const float* src = (i < 65536) ? wq : (i < 131072) ? wk : wv;
        bf16* dst = (i < 65536) ? wqT : (i < 131072) ? wkT : wvT;
        int j = i & 65535;
        int r = j >> 8, c = j & 255;
        dst[c * 256 + r] = (bf16)src[j];
        return;
    }
    i -= 3 * 65536;
    if (i < 262144) {                 // w1: [256][1024] -> w1T [1024][256]
        int r = i >> 10, c = i & 1023;
        w1T[c * 256 + r] = (bf16)w1[i];
        return;
    }
    i -= 262144;                      // w2: [1024][256] -> w2T [256][1024]
    int r = i >> 8, c = i & 255;
    w2T[c * 1024 + r] = (bf16)w2[i];
}

// ---------------- QKV projection ----------------
// grid (MTOT/64, 12); blockIdx.y: 0-3 -> q cols, 4-7 -> k cols, 8-11 -> v cols
__global__ __launch_bounds__(256) void qkv_kernel(
    const bf16* __restrict__ xb,                       // [MTOT][256]
    const bf16* __restrict__ wqT, const bf16* __restrict__ wkT, const bf16* __restrict__ wvT,
    const float* __restrict__ bq, const float* __restrict__ bk, const float* __restrict__ bv,
    bf16* __restrict__ q, bf16* __restrict__ k, bf16* __restrict__ vT) // q,k: [MTOT][256]; vT: [B][256][SEQ]
{
    __shared__ bf16 vt[64][72];
    const int lane = threadIdx.x & 63, wave = threadIdx.x >> 6;
    const int g = lane >> 4, c = lane & 15;
    const int mat = blockIdx.y >> 2;
    const int n0 = (blockIdx.y & 3) * 64;
    const int mblk = blockIdx.x * 64;
    const int m0 = mblk + wave * 16;
    const bf16* wT = (mat == 0) ? wqT : (mat == 1) ? wkT : wvT;
    const float* bias = (mat == 0) ? bq : (mat == 1) ? bk : bv;

    f32x4 acc[4] = {};
    #pragma unroll
    for (int ks = 0; ks < 8; ++ks) {
        bf16x8 a = *(const bf16x8*)(xb + (size_t)(m0 + c) * 256 + ks * 32 + 8 * g);
        #pragma unroll
        for (int nf = 0; nf < 4; ++nf) {
            bf16x8 b = *(const bf16x8*)(wT + (size_t)(n0 + nf * 16 + c) * 256 + ks * 32 + 8 * g);
            acc[nf] = MFMA_16x16x32(a, b, acc[nf]);
        }
    }
    if (mat < 2) {
        bf16* out = (mat == 0) ? q : k;
        #pragma unroll
        for (int nf = 0; nf < 4; ++nf) {
            int n = n0 + nf * 16 + c;
            float bs = bias[n];
            #pragma unroll
            for (int r = 0; r < 4; ++r)
                out[(size_t)(m0 + 4 * g + r) * 256 + n] = (bf16)(acc[nf][r] + bs);
        }
    } else {
        #pragma unroll
        for (int nf = 0; nf < 4; ++nf) {
            int n = n0 + nf * 16 + c;
            float bs = bias[n];
            #pragma unroll
            for (int r = 0; r < 4; ++r)
                vt[nf * 16 + c][wave * 16 + 4 * g + r] = (bf16)(acc[nf][r] + bs);
        }
        __syncthreads();
        int bt = mblk >> 12;        // /SEQ
        int s0 = mblk & (SEQ - 1);
        int nl = threadIdx.x >> 2;  // 0..63 -> col (n offset)
        int sc = (threadIdx.x & 3) * 16;  // row (s offset) chunk
        bf16* dst = vT + ((size_t)bt * 256 + n0 + nl) * SEQ + s0 + sc;
        const bf16x8* sp = (const bf16x8*)&vt[nl][sc];
        ((bf16x8*)dst)[0] = sp[0];
        ((bf16x8*)dst)[1] = sp[1];
    }
}

// ---------------- fused attention (flash, single-buffer 32KB LDS, swapped QK^T, KV-split x2) --
// (round-22 PASS version, byte-identical)

// chunk ch = i*256+tid; K: row=ch>>5, 16B-col=ch&31; V: d=ch>>2, s-chunk=ch&3.
#define STAGE_GLOAD(KV) do {                                                              \
    _Pragma("unroll")                                                                     \
    for (int i_ = 0; i_ < 4; ++i_) {                                                      \
        int ch_ = i_ * 256 + tid;                                                         \
        kreg[i_] = *(const bf16x8*)(kbase + (size_t)((KV) + (ch_ >> 5)) * 256 + (ch_ & 31) * 8); \
        vreg[i_] = *(const bf16x8*)(vbase + (size_t)(ch_ >> 2) * SEQ + (KV) + (ch_ & 3) * 8);    \
    } } while (0)

#define STAGE_DSWRITE() do {                                                              \
    _Pragma("unroll")                                                                     \
    for (int i_ = 0; i_ < 4; ++i_) {                                                      \
        int ch_ = i_ * 256 + tid;                                                         \
        int kr_ = ch_ >> 5, kcb_ = ch_ & 31;                                              \
        int kf_ = (kcb_ >> 2) * 2 + (kr_ >> 4);                                           \
        int kl_ = (kcb_ & 3) * 16 + (kr_ & 15);                                           \
        *(bf16x8*)&kstage[kf_][kl_ ^ ((kl_ >> 3) & 6)][0] = kreg[i_];                     \
        int vd_ = ch_ >> 2, vs_ = ch_ & 3;                                                \
        int g1_ = 2 * (vs_ & 1), jh_ = (vs_ >> 1) * 4;                                    \
        bf16x4 lo_ = ((const bf16x4*)&vreg[i_])[0];                                       \
        bf16x4 hi_ = ((const bf16x4*)&vreg[i_])[1];                                       \
        *(bf16x4*)&vstage[vd_ >> 4][g1_ * 16 + (vd_ & 15)][jh_]        = lo_;             \
        *(bf16x4*)&vstage[vd_ >> 4][g1_ * 16 + 16 + (vd_ & 15)][jh_]   = hi_;             \
    } } while (0)

#define ATTN_BODY() do {                                                                  \
    f32x4 s0 = {}, s1 = {};                                                               \
    __builtin_amdgcn_s_setprio(1);                                                        \
    _Pragma("unroll")                                                                     \
    for (int ks_ = 0; ks_ < 8; ++ks_) {                                                   \
        bf16x8 k0_ = *(const bf16x8*)&kstage[ks_ * 2 + 0][kln][0];                        \
        bf16x8 k1_ = *(const bf16x8*)&kstage[ks_ * 2 + 1][kln][0];                        \
        s0 = MFMA_16x16x32(k0_, qf[ks_], s0);                                             \
        s1 = MFMA_16x16x32(k1_, qf[ks_], s1);                                             \
    }                                                                                     \
    __builtin_amdgcn_s_setprio(0);                                                        \
    float p_[8];                                                                          \
    _Pragma("unroll")                                                                     \
    for (int r_ = 0; r_ < 4; ++r_) { p_[r_] = s0[r_] * 0.0625f; p_[4 + r_] = s1[r_] * 0.0625f; } \
    float mx = fmaxf(fmaxf(fmaxf(p_[0], p_[1]), fmaxf(p_[2], p_[3])),                     \
                     fmaxf(fmaxf(p_[4], p_[5]), fmaxf(p_[6], p_[7])));                    \
    mx = fmaxf(mx, __shfl_xor(mx, 16));                                                   \
    mx = fmaxf(mx, __shfl_xor(mx, 32));                                                   \
    if (__any(mx > m_run)) {   /* T13: rescale only when some row max grew */             \
        float mn = fmaxf(m_run, mx);                                                      \
        float a_ = __expf(m_run - mn);                                                    \
        m_run = mn; l_run *= a_;                                                          \
        float a0_ = __shfl(a_, 4 * g + 0), a1_ = __shfl(a_, 4 * g + 1);                   \
        float a2_ = __shfl(a_, 4 * g + 2), a3_ = __shfl(a_, 4 * g + 3);                   \
        _Pragma("unroll")                                                                 \
        for (int nf_ = 0; nf_ < 16; ++nf_) {                                              \
            o[nf_][0] *= a0_; o[nf_][1] *= a1_; o[nf_][2] *= a2_; o[nf_][3] *= a3_;       \
        }                                                                                 \
    }                                                                                     \
    float ls = 0.f;                                                                       \
    _Pragma("unroll")                                                                     \
    for (int j_ = 0; j_ < 8; ++j_) { p_[j_] = __expf(p_[j_] - m_run); ls += p_[j_]; }     \
    ls += __shfl_xor(ls, 16);                                                             \
    ls += __shfl_xor(ls, 32);                                                             \
    l_run += ls;                                                                          \
    bf16x8 pa;                                                                            \
    _Pragma("unroll")                                                                     \
    for (int j_ = 0; j_ < 8; ++j_) pa[j_] = (bf16)p_[j_];                                 \
    __builtin_amdgcn_s_setprio(1);                                                        \
    _Pragma("unroll")                                                                     \
    for (int nf_ = 0; nf_ < 16; ++nf_) {                                                  \
        bf16x8 v_ = *(const bf16x8*)&vstage[nf_][lane][0];                                \
        o[nf_] = MFMA_16x16x32(pa, v_, o[nf_]);                                           \
    }                                                                                     \
    __builtin_amdgcn_s_setprio(0);                                                        \
} while (0)

__global__ __launch_bounds__(256, 2) void attn_kernel(
    const bf16* __restrict__ qb, const bf16* __restrict__ kb, const bf16* __restrict__ vT,
    float* __restrict__ o_part, float* __restrict__ ml_part)
{
    __shared__ bf16 kstage[16][64][8];   // 16 KB (single buffer)
    __shared__ bf16 vstage[16][64][8];   // 16 KB
    const int tid = threadIdx.x;
    const int lane = tid & 63, wave = tid >> 6;
    const int g = lane >> 4, c = lane & 15;
    const int kln = lane ^ ((lane >> 3) & 6);   // swizzled K read slot
    const int xcd = blockIdx.x & 7, qg = blockIdx.x >> 3;   // qg 0..63
    const int bt = xcd >> 1, split = xcd & 1;
    const int mrow = bt * SEQ + qg * 64 + wave * 16;
    const int kvS = split << 11;            // this block's KV half (2048 rows)

    bf16x8 qf[8];
    #pragma unroll
    for (int ks = 0; ks < 8; ++ks)
        qf[ks] = *(const bf16x8*)(qb + (size_t)(mrow + c) * 256 + ks * 32 + 8 * g);

    f32x4 o[16] = {};
    float m_run = -1e30f, l_run = 0.f;    // per-lane: softmax state for q-row = mrow + c

    const bf16* kbase = kb + (size_t)bt * SEQ * 256;
    const bf16* vbase = vT + (size_t)bt * 256 * SEQ;

    bf16x8 kreg[4], vreg[4];
    STAGE_GLOAD(kvS);
    STAGE_DSWRITE();
    __syncthreads();

    #pragma unroll 1
    for (int t = 0; t < 64; ++t) {
        if (t < 63) STAGE_GLOAD(kvS + (t + 1) * 32);   // issue early into regs (T14)
        ATTN_BODY();                                    // compute current tile from LDS
        __syncthreads();                                // all reads of stage done
        if (t < 63) {
            STAGE_DSWRITE();                            // overwrite with next tile
            __syncthreads();                            // writes visible to all waves
        }
    }

    // epilogue: normalized FP32 partial + (m,l) fp32
    float linv = 1.f / l_run;
    float l0 = __shfl(linv, 4 * g + 0), l1 = __shfl(linv, 4 * g + 1);
    float l2 = __shfl(linv, 4 * g + 2), l3 = __shfl(linv, 4 * g + 3);
    float* op = o_part + ((size_t)split * MTOT + mrow) * 256;
    #pragma unroll
    for (int nf = 0; nf < 16; ++nf) {
        op[(size_t)(4 * g + 0) * 256 + nf * 16 + c] = o[nf][0] * l0;
        op[(size_t)(4 * g + 1) * 256 + nf * 16 + c] = o[nf][1] * l1;
        op[(size_t)(4 * g + 2) * 256 + nf * 16 + c] = o[nf][2] * l2;
        op[(size_t)(4 * g + 3) * 256 + nf * 16 + c] = o[nf][3] * l3;
    }
    if (g == 0) {
        float2 ml = make_float2(m_run, l_run);
        *(float2*)&ml_part[((size_t)split * MTOT + mrow + c) * 2] = ml;
    }
}

// ---------------- attention combine (flash merge of 2 normalized fp32 partials) ----------
__global__ __launch_bounds__(256) void attn_combine_kernel(
    const float* __restrict__ o_part, const float* __restrict__ ml_part,
    bf16* __restrict__ attn_bf)
{
    const int row = blockIdx.x * 16 + (threadIdx.x >> 4);
    const int c0 = (threadIdx.x & 15) * 16;
    float m[NSPLIT], l[NSPLIT];
    #pragma unroll
    for (int s = 0; s < NSPLIT; ++s) {
        float2 ml = *(const float2*)&ml_part[((size_t)s * MTOT + row) * 2];
        m[s] = ml.x; l[s] = ml.y;
    }
    float M = fmaxf(m[0], m[1]);
    float w[NSPLIT], L = 0.f;
    #pragma unroll
    for (int s = 0; s < NSPLIT; ++s) { w[s] = __expf(m[s] - M) * l[s]; L += w[s]; }
    float Linv = 1.f / L;
    #pragma unroll
    for (int s = 0; s < NSPLIT; ++s) w[s] *= Linv;

    float acc[16] = {};
    #pragma unroll
    for (int s = 0; s < NSPLIT; ++s) {
        const float* op = o_part + ((size_t)s * MTOT + row) * 256 + c0;
        #pragma unroll
        for (int j4 = 0; j4 < 4; ++j4) {
            float4 v = ((const float4*)op)[j4];
            acc[j4 * 4 + 0] += w[s] * v.x; acc[j4 * 4 + 1] += w[s] * v.y;
            acc[j4 * 4 + 2] += w[s] * v.z; acc[j4 * 4 + 3] += w[s] * v.w;
        }
    }
    bf16* dst = attn_bf + (size_t)row * 256 + c0;
    #pragma unroll
    for (int j = 0; j < 16; ++j) dst[j] = (bf16)acc[j];
}

// ---------------- Fused FFN: y = LN(attn + relu(attn@w1+b1)@w2 + b2) ----------------
// grid MTOT/16 = 1024 blocks x 256 thr. Block = 16 rows. FOUR 256-col quarters
// -> h_lds 8KB -> up to 8 blocks/CU under the ~64KB co-residency pool (r15/r18
// lever applied again: ffn was latency-bound at ~23% occupancy). K-accumulation
// order over k=0..1023 is unchanged vs r22 halves -> bit-identical output.
// Per quarter: phase 1 (wave computes h cols [qtr*256+64w, +64), 32 MFMA,
// swizzled write) -> barrier -> phase 2 (acc2[4] += K=256 from h_lds) -> barrier.
__global__ __launch_bounds__(256, 2) void ffn_fused_kernel(
    const bf16* __restrict__ attn, const bf16* __restrict__ w1T, const float* __restrict__ b1,
    const bf16* __restrict__ w2T, const float* __restrict__ b2,
    const float* __restrict__ ln_g, const float* __restrict__ ln_b,
    float* __restrict__ out)
{
    __shared__ bf16 h_lds[16][256];   // 8192 B
    const int lane = threadIdx.x & 63, wave = threadIdx.x >> 6;
    const int g = lane >> 4, c = lane & 15;
    const int m0 = blockIdx.x * 16;

    // attn rows (phase-1 A operand), hoisted across quarters
    bf16x8 qa[8];
    #pragma unroll
    for (int ks = 0; ks < 8; ++ks)
        qa[ks] = *(const bf16x8*)(attn + (size_t)(m0 + c) * 256 + ks * 32 + 8 * g);

    const int n2 = wave * 64;          // phase-2 output cols (fixed per wave)
    f32x4 acc2[4] = {};

    #pragma unroll 1
    for (int qtr = 0; qtr < 4; ++qtr) {
        // ---- phase 1: h cols [qtr*256 + wave*64, +64) for all 16 rows
        const int n1 = qtr * 256 + wave * 64;
        f32x4 acc1[4] = {};
        #pragma unroll
        for (int ks = 0; ks < 8; ++ks) {
            #pragma unroll
            for (int nf = 0; nf < 4; ++nf) {
                bf16x8 b = *(const bf16x8*)(w1T + (size_t)(n1 + nf * 16 + c) * 256 + ks * 32 + 8 * g);
                acc1[nf] = MFMA_16x16x32(qa[ks], b, acc1[nf]);
            }
        }
        #pragma unroll
        for (int nf = 0; nf < 4; ++nf) {
            int nl = wave * 64 + nf * 16 + c;       // local col within quarter (0..255)
            float bs = b1[qtr * 256 + nl];
            int chunk = nl >> 3, off = nl & 7;
            #pragma unroll
            for (int r = 0; r < 4; ++r) {
                int row = 4 * g + r;
                h_lds[row][((chunk ^ (row & 7)) << 3) | off] = (bf16)fmaxf(acc1[nf][r] + bs, 0.f);
            }
        }
        __syncthreads();
        // ---- phase 2: acc2 += h(quarter) @ w2(quarter rows), K = 256
        #pragma unroll 4
        for (int ks = 0; ks < 8; ++ks) {
            int chunk = 4 * ks + g;                  // 0..31
            bf16x8 a = *(const bf16x8*)&h_lds[c][(chunk ^ (c & 7)) << 3];
            #pragma unroll
            for (int nf = 0; nf < 4; ++nf) {
                bf16x8 b = *(const bf16x8*)(w2T + (size_t)(n2 + nf * 16 + c) * 1024 + qtr * 256 + ks * 32 + 8 * g);
                acc2[nf] = MFMA_16x16x32(a, b, acc2[nf]);
            }
        }
        __syncthreads();   // phase-2 reads done before next quarter overwrites
    }

    // residual + bias; per-wave LN partial sums over its 64 cols
    float sum[4] = {}, sq[4] = {};
    #pragma unroll
    for (int nf = 0; nf < 4; ++nf) {
        int col = n2 + nf * 16 + c;
        float bs = b2[col];
        #pragma unroll
        for (int r = 0; r < 4; ++r) {
            float v = acc2[nf][r] + bs + (float)attn[(size_t)(m0 + 4 * g + r) * 256 + col];
            acc2[nf][r] = v;
            sum[r] += v; sq[r] += v * v;
        }
    }
    #pragma unroll
    for (int r = 0; r < 4; ++r) {
        sum[r] += __shfl_xor(sum[r], 1); sum[r] += __shfl_xor(sum[r], 2);
        sum[r] += __shfl_xor(sum[r], 4); sum[r] += __shfl_xor(sum[r], 8);
        sq[r]  += __shfl_xor(sq[r], 1);  sq[r]  += __shfl_xor(sq[r], 2);
        sq[r]  += __shfl_xor(sq[r], 4);  sq[r]  += __shfl_xor(sq[r], 8);
    }
    // cross-wave merge via dead h_lds: sums[wave][row][2]
    float* sums = (float*)&h_lds[0][0];
    if (c == 0) {
        #pragma unroll
        for (int r = 0; r < 4; ++r) {
            sums[wave * 32 + (4 * g + r) * 2 + 0] = sum[r];
            sums[wave * 32 + (4 * g + r) * 2 + 1] = sq[r];
        }
    }
    __syncthreads();
    #pragma unroll
    for (int r = 0; r < 4; ++r) {
        int row = 4 * g + r;
        float S = sums[0 * 32 + row * 2] + sums[1 * 32 + row * 2]
                + sums[2 * 32 + row * 2] + sums[3 * 32 + row * 2];
        float Q = sums[0 * 32 + row * 2 + 1] + sums[1 * 32 + row * 2 + 1]
                + sums[2 * 32 + row * 2 + 1] + sums[3 * 32 + row * 2 + 1];
        float mean = S * (1.f / 256.f);
        float rstd = rsqrtf(Q * (1.f / 256.f) - mean * mean + 1e-5f);
        #pragma unroll
        for (int nf = 0; nf < 4; ++nf) {
            int col = n2 + nf * 16 + c;
            out[(size_t)(m0 + row) * 256 + col] = (acc2[nf][r] - mean) * rstd * ln_g[col] + ln_b[col];
        }
    }
}

// ---------------- launch ----------------
// ws layout (bytes), ~69.5 MB total (round-13..22 proved this range valid):
//   0        weights (1.44MB)
//   2097152  xb (8M)  -> attn_bf after combine
//   10485760 qb (8M)
//   18874368 kb (8M)
//   27262976 vT (8M)
//   35651584 o_part f32 [2][MTOT][256] (32M)   WRITE-ONCE, READ-ONCE, never reused
//   69206016 ml_part f32 [2][MTOT][2] (256K)   [end 69468160]
extern "C" void kernel_launch(void* const* d_in, const int* in_sizes, int n_in,
                              void* d_out, int out_size, void* d_ws, size_t ws_size,
                              hipStream_t stream) {
    const float* x    = (const float*)d_in[0];
    const float* wq   = (const float*)d_in[1];
    const float* bq   = (const float*)d_in[2];
    const float* wk   = (const float*)d_in[3];
    const float* bk   = (const float*)d_in[4];
    const float* wv   = (const float*)d_in[5];
    const float* bv   = (const float*)d_in[6];
    const float* w1   = (const float*)d_in[7];
    const float* b1   = (const float*)d_in[8];
    const float* w2   = (const float*)d_in[9];
    const float* b2   = (const float*)d_in[10];
    const float* ln_g = (const float*)d_in[11];
    const float* ln_b = (const float*)d_in[12];
    float* out = (float*)d_out;   // fp32 output

    char* ws = (char*)d_ws;
    bf16* wqT = (bf16*)(ws + 0);
    bf16* wkT = (bf16*)(ws + 131072);
    bf16* wvT = (bf16*)(ws + 262144);
    bf16* w1T = (bf16*)(ws + 393216);
    bf16* w2T = (bf16*)(ws + 917504);
    bf16* xb  = (bf16*)(ws + 2097152);
    bf16* qb  = (bf16*)(ws + 10485760);
    bf16* kb  = (bf16*)(ws + 18874368);
    bf16* vT  = (bf16*)(ws + 27262976);
    float* o_part  = (float*)(ws + 35651584);
    float* ml_part = (float*)(ws + 69206016);
    bf16* attn_bf = xb;   // xb dead after qkv

    const int PREP_N = (1048576 + 3 * 65536 + 2 * 262144) / 256;   // 6912 blocks
    prep_kernel<<<PREP_N, 256, 0, stream>>>(x, wq, wk, wv, w1, w2, xb, wqT, wkT, wvT, w1T, w2T);

    qkv_kernel<<<dim3(MTOT / 64, 12), 256, 0, stream>>>(xb, wqT, wkT, wvT, bq, bk, bv, qb, kb, vT);
    attn_kernel<<<(MTOT / 64) * NSPLIT, 256, 0, stream>>>(qb, kb, vT, o_part, ml_part);
    attn_combine_kernel<<<MTOT / 16, 256, 0, stream>>>(o_part, ml_part, attn_bf);
    ffn_fused_kernel<<<MTOT / 16, 256, 0, stream>>>(attn_bf, w1T, b1, w2T, b2, ln_g, ln_b, out);
}